// Round 3
// baseline (1597.295 us; speedup 1.0000x reference)
//
#include <hip/hip_runtime.h>
#include <math.h>

#define NB 64
#define TPB 256

// 1/k! for k = 0..15
__device__ __constant__ float CF[16] = {
    1.0f,
    1.0f,
    0.5f,
    1.6666666666666666e-01f,
    4.1666666666666664e-02f,
    8.3333333333333332e-03f,
    1.3888888888888889e-03f,
    1.9841269841269841e-04f,
    2.4801587301587302e-05f,
    2.7557319223985893e-06f,
    2.7557319223985888e-07f,
    2.5052108385441720e-08f,
    2.0876756987868100e-09f,
    1.6059043836821613e-10f,
    1.1470745597729725e-11f,
    7.6471637318198164e-13f
};

__device__ __forceinline__ void addcomp(float4& v, int d, float c) {
    switch (d) {
        case 0: v.x += c; break;
        case 1: v.y += c; break;
        case 2: v.z += c; break;
        case 3: v.w += c; break;
        default: break;
    }
}

// C = L^T * R  (+ optional  cI*I + cX*X  fused epilogue when FUSE=1)
// L must be (numerically) symmetric, so L^T == L. Reading both operands
// k-major makes the A-side loads lane-broadcast and the B-side 2-way (free).
template <int FUSE>
__device__ __forceinline__ void mm64(const float* __restrict__ L,
                                     const float* __restrict__ R,
                                     float* __restrict__ C,
                                     int i0, int j0,
                                     float cI, float cX,
                                     const float* __restrict__ X)
{
    float acc[4][4];
#pragma unroll
    for (int r = 0; r < 4; ++r)
#pragma unroll
        for (int c = 0; c < 4; ++c) acc[r][c] = 0.0f;

#pragma unroll 8
    for (int k = 0; k < NB; ++k) {
        const float4 a = *reinterpret_cast<const float4*>(L + k * NB + i0);
        const float4 b = *reinterpret_cast<const float4*>(R + k * NB + j0);
        const float av[4] = {a.x, a.y, a.z, a.w};
        const float bv[4] = {b.x, b.y, b.z, b.w};
#pragma unroll
        for (int r = 0; r < 4; ++r)
#pragma unroll
            for (int c = 0; c < 4; ++c)
                acc[r][c] = fmaf(av[r], bv[c], acc[r][c]);
    }

#pragma unroll
    for (int r = 0; r < 4; ++r) {
        float4 v = make_float4(acc[r][0], acc[r][1], acc[r][2], acc[r][3]);
        const int row = i0 + r;
        const int off = row * NB + j0;
        if (FUSE) {
            const float4 x = *reinterpret_cast<const float4*>(X + off);
            v.x = fmaf(cX, x.x, v.x);
            v.y = fmaf(cX, x.y, v.y);
            v.z = fmaf(cX, x.z, v.z);
            v.w = fmaf(cX, x.w, v.w);
            const int d = row - j0;
            if (d >= 0 && d < 4) addcomp(v, d, cI);
        }
        *reinterpret_cast<float4*>(C + off) = v;
    }
}

__global__ __launch_bounds__(TPB, 2)
void spd_expmap_kernel(const float* __restrict__ in, float* __restrict__ out)
{
    __shared__ float sX [NB * NB];   // A, then X = A / 2^s
    __shared__ float sX2[NB * NB];   // A^2, then X^2
    __shared__ float sB0[NB * NB];
    __shared__ float sB1[NB * NB];
    __shared__ int   sexp_sh;

    const int tid = threadIdx.x;
    const int ty = tid >> 4;
    const int tx = tid & 15;
    const int i0 = ty * 4;
    const int j0 = tx * 4;
    const size_t base = (size_t)blockIdx.x * (NB * NB);

    // ---- load A (coalesced float4) ----
    {
        const float4* gin = reinterpret_cast<const float4*>(in + base);
        float4* dst = reinterpret_cast<float4*>(sX);
#pragma unroll
        for (int i = 0; i < 4; ++i)
            dst[tid + i * TPB] = gin[tid + i * TPB];
    }
    __syncthreads();

    // ---- A2 = A^T * A = A^2 (A exactly symmetric) ----
    mm64<0>(sX, sX, sX2, i0, j0, 0.f, 0.f, nullptr);
    __syncthreads();

    // ---- spectral-norm bound: ||A||_2 <= sqrt(||A^2||_inf); pick s ----
    if (tid < 64) {
        float ssum = 0.0f;
        // A^2 is exactly symmetric; read column tid (stride-64 rows -> 2-way banks, free)
        for (int j = 0; j < NB; ++j)
            ssum += fabsf(sX2[j * NB + tid]);
#pragma unroll
        for (int off = 32; off > 0; off >>= 1)
            ssum = fmaxf(ssum, __shfl_xor(ssum, off));
        if (tid == 0) {
            float bound = sqrtf(ssum);
            int s = 0;
            if (bound > 1.0f) {
                s = (int)ceilf(log2f(bound));
                if (s < 0) s = 0;
                if (s > 24) s = 24;
            }
            sexp_sh = s;
        }
    }
    __syncthreads();

    const int   sexp = sexp_sh;
    const float sc1  = exp2f(-(float)sexp);
    const float sc2  = sc1 * sc1;

    // ---- scale: X = A/2^s, X2 = A^2/4^s ----
    {
        float4* pX  = reinterpret_cast<float4*>(sX);
        float4* pX2 = reinterpret_cast<float4*>(sX2);
#pragma unroll
        for (int i = 0; i < 4; ++i) {
            const int idx = tid + i * TPB;
            float4 v = pX[idx];
            v.x *= sc1; v.y *= sc1; v.z *= sc1; v.w *= sc1;
            pX[idx] = v;
            float4 w = pX2[idx];
            w.x *= sc2; w.y *= sc2; w.z *= sc2; w.w *= sc2;
            pX2[idx] = w;
        }
    }
    __syncthreads();

    // ---- init P = B7 = CF[14]*I + CF[15]*X  (degree-15 Taylor, chunk-2 PS) ----
    {
        const float4* pX = reinterpret_cast<const float4*>(sX);
        float4* pP = reinterpret_cast<float4*>(sB0);
        const float c14 = CF[14], c15 = CF[15];
#pragma unroll
        for (int i = 0; i < 4; ++i) {
            const int idx = tid + i * TPB;
            const float4 x = pX[idx];
            float4 v = make_float4(c15 * x.x, c15 * x.y, c15 * x.z, c15 * x.w);
            const int g = idx * 4;
            const int row = g >> 6;
            const int col = g & 63;
            const int d = row - col;
            if (d >= 0 && d < 4) addcomp(v, d, c14);
            pP[idx] = v;
        }
    }
    __syncthreads();

    // ---- outer Horner in Y = X^2:  P = Bj + Y*P,  j = 6..0 ----
    float* Pb = sB0;
    float* Tb = sB1;
#pragma unroll 1
    for (int j = 6; j >= 0; --j) {
        mm64<1>(sX2, Pb, Tb, i0, j0, CF[2 * j], CF[2 * j + 1], sX);
        float* t = Pb; Pb = Tb; Tb = t;
        __syncthreads();
    }

    // ---- s squarings: P <- P^T * P (exactly symmetric result) ----
    for (int t = 0; t < sexp; ++t) {
        mm64<0>(Pb, Pb, Tb, i0, j0, 0.f, 0.f, nullptr);
        float* tt = Pb; Pb = Tb; Tb = tt;
        __syncthreads();
    }

    // ---- store (coalesced float4) ----
    {
        const float4* src = reinterpret_cast<const float4*>(Pb);
        float4* gout = reinterpret_cast<float4*>(out + base);
#pragma unroll
        for (int i = 0; i < 4; ++i)
            gout[tid + i * TPB] = src[tid + i * TPB];
    }
}

extern "C" void kernel_launch(void* const* d_in, const int* in_sizes, int n_in,
                              void* d_out, int out_size, void* d_ws, size_t ws_size,
                              hipStream_t stream) {
    const float* in = reinterpret_cast<const float*>(d_in[0]);
    float* out = reinterpret_cast<float*>(d_out);
    const int nmat = in_sizes[0] / (NB * NB);
    hipLaunchKernelGGL(spd_expmap_kernel, dim3(nmat), dim3(TPB), 0, stream, in, out);
}

// Round 5
// 488.440 us; speedup vs baseline: 3.2702x; 3.2702x over previous
//
#include <hip/hip_runtime.h>
#include <math.h>

#define NB 64
#define TPB 256

// 1/k! for k = 0..15
__device__ __constant__ float CF[16] = {
    1.0f,
    1.0f,
    0.5f,
    1.6666666666666666e-01f,
    4.1666666666666664e-02f,
    8.3333333333333332e-03f,
    1.3888888888888889e-03f,
    1.9841269841269841e-04f,
    2.4801587301587302e-05f,
    2.7557319223985893e-06f,
    2.7557319223985888e-07f,
    2.5052108385441720e-08f,
    2.0876756987868100e-09f,
    1.6059043836821613e-10f,
    1.1470745597729725e-11f,
    7.6471637318198164e-13f
};

typedef __attribute__((ext_vector_type(8))) short bf16x8;
typedef __attribute__((ext_vector_type(16))) float f32x16;
typedef __attribute__((ext_vector_type(4))) unsigned int u32x4;

#define MFMA32 __builtin_amdgcn_mfma_f32_32x32x16_bf16

__device__ __forceinline__ unsigned short f2bf(float x) {
    unsigned u = __builtin_bit_cast(unsigned, x);
    u += 0x7FFFu + ((u >> 16) & 1u);          // RNE
    return (unsigned short)(u >> 16);
}
__device__ __forceinline__ float bf2f(unsigned short h) {
    unsigned u = ((unsigned)h) << 16;
    return __builtin_bit_cast(float, u);
}
__device__ __forceinline__ void split2(float x, unsigned short& h, unsigned short& l) {
    h = f2bf(x);
    l = f2bf(x - bf2f(h));
}

// byte offset of (row, byteInRow) in a swizzled 64x64 bf16 LDS matrix (128 B rows)
__device__ __forceinline__ unsigned swzoff(int row, int byteInRow) {
    return (unsigned)(row * 128 + (byteInRow ^ ((row & 7) << 4)));
}

// A/B fragment for v_mfma_f32_32x32x16_bf16, k-step f (k in [16f,16f+16)).
// lane: row = rowbase + (lane&31), k = 16f + 8*(lane>>5) + 0..7  -> 16B read.
__device__ __forceinline__ bf16x8 ldfrag(const unsigned short* buf, int row, int f, int lh) {
    const char* p = (const char*)buf + swzoff(row, f * 32 + lh * 16);
    return __builtin_bit_cast(bf16x8, *(const u32x4*)p);
}

// acc = Ahi*Bhi + Alo*Bhi + Ahi*Blo  over K=64 (4 k-steps each)
__device__ __forceinline__ f32x16 mm3(const bf16x8* ah, const bf16x8* al,
                                      const bf16x8* bh, const bf16x8* bl) {
    f32x16 acc = {};
#pragma unroll
    for (int f = 0; f < 4; ++f) acc = MFMA32(ah[f], bh[f], acc, 0, 0, 0);
#pragma unroll
    for (int f = 0; f < 4; ++f) acc = MFMA32(al[f], bh[f], acc, 0, 0, 0);
#pragma unroll
    for (int f = 0; f < 4; ++f) acc = MFMA32(ah[f], bl[f], acc, 0, 0, 0);
    return acc;
}

// Split v[16] into hi/lo bf16 and write TRANSPOSED: value (row r_out, col c_out)
// goes to LDS[c_out][r_out]; 4 consecutive rows per reg-group -> one ds_write_b64.
__device__ __forceinline__ void store_cT(unsigned short* Bh, unsigned short* Bl,
                                         const float* v, int c_out, int rbase) {
#pragma unroll
    for (int g = 0; g < 4; ++g) {
        unsigned short h[4], l[4];
#pragma unroll
        for (int q = 0; q < 4; ++q) split2(v[g * 4 + q], h[q], l[q]);
        uint2 wh = make_uint2((unsigned)h[0] | ((unsigned)h[1] << 16),
                              (unsigned)h[2] | ((unsigned)h[3] << 16));
        uint2 wl = make_uint2((unsigned)l[0] | ((unsigned)l[1] << 16),
                              (unsigned)l[2] | ((unsigned)l[3] << 16));
        unsigned off = swzoff(c_out, (rbase + g * 8) * 2);
        *(uint2*)((char*)Bh + off) = wh;
        *(uint2*)((char*)Bl + off) = wl;
    }
}

__global__ __launch_bounds__(TPB, 2)
void spd_expmap_mfma(const float* __restrict__ in, float* __restrict__ out)
{
    __shared__ __align__(16) unsigned short SB[6 * 4096];
    __shared__ float wsum[4];
    unsigned short* Xhi = SB;
    unsigned short* Xlo = SB + 4096;
    unsigned short* Yhi = SB + 8192;
    unsigned short* Ylo = SB + 12288;
    unsigned short* Phi = SB + 16384;
    unsigned short* Plo = SB + 20480;

    const int tid  = threadIdx.x;
    const int lane = tid & 63;
    const int wv   = tid >> 6;
    const int wr   = (wv >> 1) * 32;   // wave's output row-block
    const int wc   = (wv & 1) * 32;    // wave's output col-block
    const int l31  = lane & 31;
    const int lh   = lane >> 5;
    const int c_out = wc + l31;                 // C/D: col = lane&31
    const int rbase = wr + 4 * lh;              // C/D: row = (reg&3)+8*(reg>>2)+4*(lane>>5)
    const size_t base = (size_t)blockIdx.x * (NB * NB);

    unsigned dmask = 0;
#pragma unroll
    for (int g = 0; g < 4; ++g)
#pragma unroll
        for (int q = 0; q < 4; ++q)
            if (rbase + g * 8 + q == c_out) dmask |= 1u << (g * 4 + q);

    // ---- load A (fp32, coalesced-ish), split hi/lo, store swizzled ----
    {
        const int r  = tid >> 2;
        const int cb = (tid & 3) * 16;
        const float4* gp = (const float4*)(in + base) + tid * 4;
        float vv[16];
#pragma unroll
        for (int i = 0; i < 4; ++i) {
            float4 t = gp[i];
            vv[i * 4 + 0] = t.x; vv[i * 4 + 1] = t.y;
            vv[i * 4 + 2] = t.z; vv[i * 4 + 3] = t.w;
        }
        unsigned hw[8], lw[8];
#pragma unroll
        for (int i = 0; i < 8; ++i) {
            unsigned short h0, l0, h1, l1;
            split2(vv[2 * i], h0, l0);
            split2(vv[2 * i + 1], h1, l1);
            hw[i] = (unsigned)h0 | ((unsigned)h1 << 16);
            lw[i] = (unsigned)l0 | ((unsigned)l1 << 16);
        }
        u32x4 H0 = {hw[0], hw[1], hw[2], hw[3]}, H1 = {hw[4], hw[5], hw[6], hw[7]};
        u32x4 L0 = {lw[0], lw[1], lw[2], lw[3]}, L1 = {lw[4], lw[5], lw[6], lw[7]};
        unsigned o0 = swzoff(r, cb * 2), o1 = swzoff(r, cb * 2 + 16);
        *(u32x4*)((char*)Xhi + o0) = H0; *(u32x4*)((char*)Xhi + o1) = H1;
        *(u32x4*)((char*)Xlo + o0) = L0; *(u32x4*)((char*)Xlo + o1) = L1;
    }
    __syncthreads();

    // ---- mm1: Y = A*A (split product); fused Frobenius(A^2) for s ----
    {
        bf16x8 ah[4], al[4], bh[4], bl[4];
#pragma unroll
        for (int f = 0; f < 4; ++f) {
            ah[f] = ldfrag(Xhi, wr + l31, f, lh);
            al[f] = ldfrag(Xlo, wr + l31, f, lh);
            bh[f] = ldfrag(Xhi, wc + l31, f, lh);
            bl[f] = ldfrag(Xlo, wc + l31, f, lh);
        }
        f32x16 acc = mm3(ah, al, bh, bl);
        float v[16]; float fr = 0.f;
#pragma unroll
        for (int r = 0; r < 16; ++r) { v[r] = acc[r]; fr += v[r] * v[r]; }
#pragma unroll
        for (int off = 32; off; off >>= 1) fr += __shfl_xor(fr, off);
        if (lane == 0) wsum[wv] = fr;
        store_cT(Yhi, Ylo, v, c_out, rbase);
    }
    __syncthreads();

    // ||A||_2 = sqrt(||A^2||_2) <= sqrt(||A^2||_F) = (sum (A^2)_ij^2)^(1/4)
    const float total = wsum[0] + wsum[1] + wsum[2] + wsum[3];
    const float bound = sqrtf(sqrtf(total));
    int sexp = 0;
    if (bound > 1.f) {
        sexp = (int)ceilf(log2f(bound));
        if (sexp < 0) sexp = 0;
        if (sexp > 24) sexp = 24;
    }
    const float sc1 = exp2f(-(float)sexp);

    // ---- exact in-place scale: X *= 2^-s, Y *= 4^-s (power-of-2 => mantissa preserved) ----
    {
        const float sc2 = sc1 * sc1;
        unsigned* pXall = (unsigned*)SB;            // Xhi+Xlo = 4096 u32
        unsigned* pYall = (unsigned*)(SB + 8192);   // Yhi+Ylo = 4096 u32
#pragma unroll
        for (int i = 0; i < 16; ++i) {
            const int idx = tid + i * TPB;
            unsigned u = pXall[idx];
            float a = bf2f((unsigned short)(u & 0xFFFF)) * sc1;
            float b = bf2f((unsigned short)(u >> 16)) * sc1;
            pXall[idx] = (__builtin_bit_cast(unsigned, a) >> 16)
                       | ((__builtin_bit_cast(unsigned, b) >> 16) << 16);
            unsigned w = pYall[idx];
            float c = bf2f((unsigned short)(w & 0xFFFF)) * sc2;
            float d = bf2f((unsigned short)(w >> 16)) * sc2;
            pYall[idx] = (__builtin_bit_cast(unsigned, c) >> 16)
                       | ((__builtin_bit_cast(unsigned, d) >> 16) << 16);
        }
    }
    __syncthreads();

    // ---- x_out regs: X at this lane's 16 output positions (X exactly symmetric) ----
    float x_out[16];
#pragma unroll
    for (int g = 0; g < 4; ++g) {
        unsigned off = swzoff(c_out, (rbase + g * 8) * 2);
        uint2 xh = *(const uint2*)((const char*)Xhi + off);
        uint2 xl = *(const uint2*)((const char*)Xlo + off);
        x_out[g * 4 + 0] = bf2f((unsigned short)(xh.x & 0xFFFF)) + bf2f((unsigned short)(xl.x & 0xFFFF));
        x_out[g * 4 + 1] = bf2f((unsigned short)(xh.x >> 16))    + bf2f((unsigned short)(xl.x >> 16));
        x_out[g * 4 + 2] = bf2f((unsigned short)(xh.y & 0xFFFF)) + bf2f((unsigned short)(xl.y & 0xFFFF));
        x_out[g * 4 + 3] = bf2f((unsigned short)(xh.y >> 16))    + bf2f((unsigned short)(xl.y >> 16));
    }

    // ---- resident Y A-side fragments (loop-invariant over Horner) ----
    bf16x8 ya_h[4], ya_l[4];
#pragma unroll
    for (int f = 0; f < 4; ++f) {
        ya_h[f] = ldfrag(Yhi, wr + l31, f, lh);
        ya_l[f] = ldfrag(Ylo, wr + l31, f, lh);
    }

    // ---- P init = CF[14]*I + CF[15]*X ----
    {
        float v[16];
#pragma unroll
        for (int r = 0; r < 16; ++r)
            v[r] = CF[15] * x_out[r] + (((dmask >> r) & 1) ? CF[14] : 0.f);
        store_cT(Phi, Plo, v, c_out, rbase);
    }
    __syncthreads();

    // ---- Horner in Y = X^2:  P <- (c2j*I + c2j+1*X) + Y*P,  j = 6..0 ----
#pragma unroll 1
    for (int j = 6; j >= 0; --j) {
        bf16x8 pbh[4], pbl[4];
#pragma unroll
        for (int f = 0; f < 4; ++f) {
            pbh[f] = ldfrag(Phi, wc + l31, f, lh);
            pbl[f] = ldfrag(Plo, wc + l31, f, lh);
        }
        f32x16 acc = mm3(ya_h, ya_l, pbh, pbl);
        __syncthreads();                 // all waves done reading P
        float v[16];
        const float cI = CF[2 * j], cX = CF[2 * j + 1];
#pragma unroll
        for (int r = 0; r < 16; ++r)
            v[r] = acc[r] + cX * x_out[r] + (((dmask >> r) & 1) ? cI : 0.f);
        store_cT(Phi, Plo, v, c_out, rbase);
        __syncthreads();                 // writes visible
    }

    // ---- s squarings: P <- P*P ----
#pragma unroll 1
    for (int t = 0; t < sexp; ++t) {
        bf16x8 pah[4], pal[4], pbh[4], pbl[4];
#pragma unroll
        for (int f = 0; f < 4; ++f) {
            pah[f] = ldfrag(Phi, wr + l31, f, lh);
            pal[f] = ldfrag(Plo, wr + l31, f, lh);
            pbh[f] = ldfrag(Phi, wc + l31, f, lh);
            pbl[f] = ldfrag(Plo, wc + l31, f, lh);
        }
        f32x16 acc = mm3(pah, pal, pbh, pbl);
        __syncthreads();
        float v[16];
#pragma unroll
        for (int r = 0; r < 16; ++r) v[r] = acc[r];
        store_cT(Phi, Plo, v, c_out, rbase);
        __syncthreads();
    }

    // ---- store out = Phi + Plo as fp32 (coalesced-ish) ----
    {
        const int r  = tid >> 2;
        const int cb = (tid & 3) * 16;
        unsigned o0 = swzoff(r, cb * 2), o1 = swzoff(r, cb * 2 + 16);
        u32x4 H0 = *(const u32x4*)((const char*)Phi + o0);
        u32x4 H1 = *(const u32x4*)((const char*)Phi + o1);
        u32x4 L0 = *(const u32x4*)((const char*)Plo + o0);
        u32x4 L1 = *(const u32x4*)((const char*)Plo + o1);
        float vv[16];
#pragma unroll
        for (int i = 0; i < 4; ++i) {
            vv[2 * i]         = bf2f((unsigned short)(H0[i] & 0xFFFF)) + bf2f((unsigned short)(L0[i] & 0xFFFF));
            vv[2 * i + 1]     = bf2f((unsigned short)(H0[i] >> 16))    + bf2f((unsigned short)(L0[i] >> 16));
            vv[8 + 2 * i]     = bf2f((unsigned short)(H1[i] & 0xFFFF)) + bf2f((unsigned short)(L1[i] & 0xFFFF));
            vv[8 + 2 * i + 1] = bf2f((unsigned short)(H1[i] >> 16))    + bf2f((unsigned short)(L1[i] >> 16));
        }
        float4* gp = (float4*)(out + base) + tid * 4;
#pragma unroll
        for (int i = 0; i < 4; ++i) {
            float4 t;
            t.x = vv[4 * i]; t.y = vv[4 * i + 1]; t.z = vv[4 * i + 2]; t.w = vv[4 * i + 3];
            gp[i] = t;
        }
    }
}

extern "C" void kernel_launch(void* const* d_in, const int* in_sizes, int n_in,
                              void* d_out, int out_size, void* d_ws, size_t ws_size,
                              hipStream_t stream) {
    const float* in = reinterpret_cast<const float*>(d_in[0]);
    float* out = reinterpret_cast<float*>(d_out);
    const int nmat = in_sizes[0] / (NB * NB);
    hipLaunchKernelGGL(spd_expmap_mfma, dim3(nmat), dim3(TPB), 0, stream, in, out);
}

// Round 6
// 335.534 us; speedup vs baseline: 4.7605x; 1.4557x over previous
//
#include <hip/hip_runtime.h>
#include <math.h>

#define NB 64
#define TPB 256

// 1/k! for k = 0..15
__device__ __constant__ float CF[16] = {
    1.0f,
    1.0f,
    0.5f,
    1.6666666666666666e-01f,
    4.1666666666666664e-02f,
    8.3333333333333332e-03f,
    1.3888888888888889e-03f,
    1.9841269841269841e-04f,
    2.4801587301587302e-05f,
    2.7557319223985893e-06f,
    2.7557319223985888e-07f,
    2.5052108385441720e-08f,
    2.0876756987868100e-09f,
    1.6059043836821613e-10f,
    1.1470745597729725e-11f,
    7.6471637318198164e-13f
};

typedef __attribute__((ext_vector_type(8))) short bf16x8;
typedef __attribute__((ext_vector_type(16))) float f32x16;
typedef __attribute__((ext_vector_type(4))) unsigned int u32x4;

#define MFMA32 __builtin_amdgcn_mfma_f32_32x32x16_bf16

// packed split: (x0,x1) -> hi word (bf16(x0)|bf16(x1)<<16), lo word (residuals)
__device__ __forceinline__ void split_pk(float x0, float x1, unsigned& ph, unsigned& pl) {
    unsigned h;
    asm("v_cvt_pk_bf16_f32 %0, %1, %2" : "=v"(h) : "v"(x0), "v"(x1));
    float h0 = __builtin_bit_cast(float, h << 16);
    float h1 = __builtin_bit_cast(float, h & 0xFFFF0000u);
    float r0 = x0 - h0;
    float r1 = x1 - h1;
    unsigned l;
    asm("v_cvt_pk_bf16_f32 %0, %1, %2" : "=v"(l) : "v"(r0), "v"(r1));
    ph = h; pl = l;
}

__device__ __forceinline__ float bf2f(unsigned short h) {
    unsigned u = ((unsigned)h) << 16;
    return __builtin_bit_cast(float, u);
}

// byte offset of (row, byteInRow) in a swizzled 64x64 bf16 LDS matrix (128 B rows)
__device__ __forceinline__ unsigned swzoff(int row, int byteInRow) {
    return (unsigned)(row * 128 + (byteInRow ^ ((row & 7) << 4)));
}

// A/B fragment for v_mfma_f32_32x32x16_bf16, k-step f (k in [16f,16f+16)).
// lane: row = rowbase + (lane&31), k = 16f + 8*(lane>>5) + 0..7  -> 16B read.
__device__ __forceinline__ bf16x8 ldfrag(const unsigned short* buf, int row, int f, int lh) {
    const char* p = (const char*)buf + swzoff(row, f * 32 + lh * 16);
    return __builtin_bit_cast(bf16x8, *(const u32x4*)p);
}

// acc = Ahi*Bhi + Alo*Bhi + Ahi*Blo  over K=64 (4 k-steps each)
__device__ __forceinline__ f32x16 mm3(const bf16x8* ah, const bf16x8* al,
                                      const bf16x8* bh, const bf16x8* bl) {
    f32x16 acc = {};
#pragma unroll
    for (int f = 0; f < 4; ++f) acc = MFMA32(ah[f], bh[f], acc, 0, 0, 0);
#pragma unroll
    for (int f = 0; f < 4; ++f) acc = MFMA32(al[f], bh[f], acc, 0, 0, 0);
#pragma unroll
    for (int f = 0; f < 4; ++f) acc = MFMA32(ah[f], bl[f], acc, 0, 0, 0);
    return acc;
}

// Split v[16] into hi/lo bf16 and write TRANSPOSED: value (row r_out, col c_out)
// goes to LDS[c_out][r_out]; 4 consecutive rows per reg-group -> one ds_write_b64.
__device__ __forceinline__ void store_cT(unsigned short* Bh, unsigned short* Bl,
                                         const float* v, int c_out, int rbase) {
#pragma unroll
    for (int g = 0; g < 4; ++g) {
        uint2 wh, wl;
        split_pk(v[g * 4 + 0], v[g * 4 + 1], wh.x, wl.x);
        split_pk(v[g * 4 + 2], v[g * 4 + 3], wh.y, wl.y);
        unsigned off = swzoff(c_out, (rbase + g * 8) * 2);
        *(uint2*)((char*)Bh + off) = wh;
        *(uint2*)((char*)Bl + off) = wl;
    }
}

__global__ __launch_bounds__(TPB, 4)
void spd_expmap_mfma(const float* __restrict__ in, float* __restrict__ out)
{
    // Two hi/lo buffer pairs, 32 KiB total.
    // B0 = X, later P (ping).  B1 = Y, later P (pong).
    __shared__ __align__(16) unsigned short SB[4 * 4096];
    __shared__ float wsum[4];
    unsigned short* B0h = SB;
    unsigned short* B0l = SB + 4096;
    unsigned short* B1h = SB + 8192;
    unsigned short* B1l = SB + 12288;

    const int tid  = threadIdx.x;
    const int lane = tid & 63;
    const int wv   = tid >> 6;
    const int wr   = (wv >> 1) * 32;   // wave's output row-block
    const int wc   = (wv & 1) * 32;    // wave's output col-block
    const int l31  = lane & 31;
    const int lh   = lane >> 5;
    const int c_out = wc + l31;                 // C/D: col = lane&31
    const int rbase = wr + 4 * lh;              // C/D: row = (reg&3)+8*(reg>>2)+4*(lane>>5)
    const size_t base = (size_t)blockIdx.x * (NB * NB);

    unsigned dmask = 0;
#pragma unroll
    for (int g = 0; g < 4; ++g)
#pragma unroll
        for (int q = 0; q < 4; ++q)
            if (rbase + g * 8 + q == c_out) dmask |= 1u << (g * 4 + q);

    // ---- load A (fp32), split hi/lo (packed cvt), store swizzled into B0 ----
    {
        const int r  = tid >> 2;
        const int cb = (tid & 3) * 16;
        const float4* gp = (const float4*)(in + base) + tid * 4;
        float vv[16];
#pragma unroll
        for (int i = 0; i < 4; ++i) {
            float4 t = gp[i];
            vv[i * 4 + 0] = t.x; vv[i * 4 + 1] = t.y;
            vv[i * 4 + 2] = t.z; vv[i * 4 + 3] = t.w;
        }
        unsigned hw[8], lw[8];
#pragma unroll
        for (int i = 0; i < 8; ++i)
            split_pk(vv[2 * i], vv[2 * i + 1], hw[i], lw[i]);
        u32x4 H0 = {hw[0], hw[1], hw[2], hw[3]}, H1 = {hw[4], hw[5], hw[6], hw[7]};
        u32x4 L0 = {lw[0], lw[1], lw[2], lw[3]}, L1 = {lw[4], lw[5], lw[6], lw[7]};
        unsigned o0 = swzoff(r, cb * 2), o1 = swzoff(r, cb * 2 + 16);
        *(u32x4*)((char*)B0h + o0) = H0; *(u32x4*)((char*)B0h + o1) = H1;
        *(u32x4*)((char*)B0l + o0) = L0; *(u32x4*)((char*)B0l + o1) = L1;
    }
    __syncthreads();

    // ---- mm1: acc = A*A (split product) + Frobenius(A^2) reduction ----
    f32x16 acc;
    {
        bf16x8 ah[4], al[4], bh[4], bl[4];
#pragma unroll
        for (int f = 0; f < 4; ++f) {
            ah[f] = ldfrag(B0h, wr + l31, f, lh);
            al[f] = ldfrag(B0l, wr + l31, f, lh);
            bh[f] = ldfrag(B0h, wc + l31, f, lh);
            bl[f] = ldfrag(B0l, wc + l31, f, lh);
        }
        acc = mm3(ah, al, bh, bl);
        float fr = 0.f;
#pragma unroll
        for (int r = 0; r < 16; ++r) fr += acc[r] * acc[r];
#pragma unroll
        for (int off = 32; off; off >>= 1) fr += __shfl_xor(fr, off);
        if (lane == 0) wsum[wv] = fr;
    }
    __syncthreads();   // wsum visible; all X-frag reads drained (B0 safe to overwrite)

    // ||A||_2 <= (sum (A^2)_ij^2)^(1/4); tolerate ||X|| <= 2 (deg-13 remainder ~2e-7)
    const float total = wsum[0] + wsum[1] + wsum[2] + wsum[3];
    const float bound = sqrtf(sqrtf(total));
    int sexp = 0;
    if (bound > 2.f) {
        sexp = (int)ceilf(log2f(bound)) - 1;
        if (sexp < 0) sexp = 0;
        if (sexp > 24) sexp = 24;
    }
    const float sc1 = exp2f(-(float)sexp);
    const float sc2 = sc1 * sc1;

    // ---- Y = acc * 4^-s  -> split-store into B1 (pre-scaled; no LDS rescale pass) ----
    {
        float v[16];
#pragma unroll
        for (int r = 0; r < 16; ++r) v[r] = acc[r] * sc2;
        store_cT(B1h, B1l, v, c_out, rbase);
    }

    // ---- x_out: X at this lane's OWN output positions (same addrs it wrote), scaled in regs ----
    float x_out[16];
#pragma unroll
    for (int g = 0; g < 4; ++g) {
        unsigned off = swzoff(c_out, (rbase + g * 8) * 2);
        uint2 xh = *(const uint2*)((const char*)B0h + off);
        uint2 xl = *(const uint2*)((const char*)B0l + off);
        x_out[g * 4 + 0] = (bf2f((unsigned short)(xh.x & 0xFFFF)) + bf2f((unsigned short)(xl.x & 0xFFFF))) * sc1;
        x_out[g * 4 + 1] = (bf2f((unsigned short)(xh.x >> 16))    + bf2f((unsigned short)(xl.x >> 16)))    * sc1;
        x_out[g * 4 + 2] = (bf2f((unsigned short)(xh.y & 0xFFFF)) + bf2f((unsigned short)(xl.y & 0xFFFF))) * sc1;
        x_out[g * 4 + 3] = (bf2f((unsigned short)(xh.y >> 16))    + bf2f((unsigned short)(xl.y >> 16)))    * sc1;
    }

    // ---- P init = CF[12]*I + CF[13]*X -> B0 (own positions only; X consumed) ----
    {
        float v[16];
#pragma unroll
        for (int r = 0; r < 16; ++r)
            v[r] = CF[13] * x_out[r] + (((dmask >> r) & 1) ? CF[12] : 0.f);
        store_cT(B0h, B0l, v, c_out, rbase);
    }
    __syncthreads();   // Y (B1) + P-init (B0) visible

    // ---- resident Y A-side fragments ----
    bf16x8 ya_h[4], ya_l[4];
#pragma unroll
    for (int f = 0; f < 4; ++f) {
        ya_h[f] = ldfrag(B1h, wr + l31, f, lh);
        ya_l[f] = ldfrag(B1l, wr + l31, f, lh);
    }
    __syncthreads();   // Y-frag reads drained before Horner overwrites B1

    // ---- Horner (degree-13, chunk-2):  P <- (c2j*I + c2j+1*X) + Y*P,  j = 5..0 ----
    unsigned short* curh = B0h; unsigned short* curl = B0l;
    unsigned short* nxth = B1h; unsigned short* nxtl = B1l;
#pragma unroll 1
    for (int j = 5; j >= 0; --j) {
        bf16x8 pbh[4], pbl[4];
#pragma unroll
        for (int f = 0; f < 4; ++f) {
            pbh[f] = ldfrag(curh, wc + l31, f, lh);
            pbl[f] = ldfrag(curl, wc + l31, f, lh);
        }
        f32x16 a2 = mm3(ya_h, ya_l, pbh, pbl);
        float w[16];
        const float cI = CF[2 * j], cX = CF[2 * j + 1];
#pragma unroll
        for (int r = 0; r < 16; ++r)
            w[r] = a2[r] + cX * x_out[r] + (((dmask >> r) & 1) ? cI : 0.f);
        store_cT(nxth, nxtl, w, c_out, rbase);
        unsigned short* th = curh; curh = nxth; nxth = th;
        unsigned short* tl = curl; curl = nxtl; nxtl = tl;
        __syncthreads();   // one barrier per stage (ping-pong)
    }

    // ---- s squarings: P <- P*P; final result written straight to global ----
#pragma unroll 1
    for (int t = 0; t < sexp; ++t) {
        bf16x8 pah[4], pal[4], pbh[4], pbl[4];
#pragma unroll
        for (int f = 0; f < 4; ++f) {
            pah[f] = ldfrag(curh, wr + l31, f, lh);
            pal[f] = ldfrag(curl, wr + l31, f, lh);
            pbh[f] = ldfrag(curh, wc + l31, f, lh);
            pbl[f] = ldfrag(curl, wc + l31, f, lh);
        }
        f32x16 a2 = mm3(pah, pal, pbh, pbl);
        if (t == sexp - 1) {
            // final: fp32 straight from acc (col-contiguous across lanes -> coalesced)
#pragma unroll
            for (int g = 0; g < 4; ++g)
#pragma unroll
                for (int q = 0; q < 4; ++q)
                    out[base + (size_t)(rbase + g * 8 + q) * NB + c_out] = a2[g * 4 + q];
        } else {
            float w[16];
#pragma unroll
            for (int r = 0; r < 16; ++r) w[r] = a2[r];
            store_cT(nxth, nxtl, w, c_out, rbase);
            unsigned short* th = curh; curh = nxth; nxth = th;
            unsigned short* tl = curl; curl = nxtl; nxtl = tl;
            __syncthreads();
        }
    }

    if (sexp == 0) {
        // No squarings: P (hi+lo in cur) is the answer; own positions, no barrier needed.
#pragma unroll
        for (int g = 0; g < 4; ++g) {
            unsigned off = swzoff(c_out, (rbase + g * 8) * 2);
            uint2 ph = *(const uint2*)((const char*)curh + off);
            uint2 pl = *(const uint2*)((const char*)curl + off);
            float v0 = bf2f((unsigned short)(ph.x & 0xFFFF)) + bf2f((unsigned short)(pl.x & 0xFFFF));
            float v1 = bf2f((unsigned short)(ph.x >> 16))    + bf2f((unsigned short)(pl.x >> 16));
            float v2 = bf2f((unsigned short)(ph.y & 0xFFFF)) + bf2f((unsigned short)(pl.y & 0xFFFF));
            float v3 = bf2f((unsigned short)(ph.y >> 16))    + bf2f((unsigned short)(pl.y >> 16));
            out[base + (size_t)(rbase + g * 8 + 0) * NB + c_out] = v0;
            out[base + (size_t)(rbase + g * 8 + 1) * NB + c_out] = v1;
            out[base + (size_t)(rbase + g * 8 + 2) * NB + c_out] = v2;
            out[base + (size_t)(rbase + g * 8 + 3) * NB + c_out] = v3;
        }
    }
}

extern "C" void kernel_launch(void* const* d_in, const int* in_sizes, int n_in,
                              void* d_out, int out_size, void* d_ws, size_t ws_size,
                              hipStream_t stream) {
    const float* in = reinterpret_cast<const float*>(d_in[0]);
    float* out = reinterpret_cast<float*>(d_out);
    const int nmat = in_sizes[0] / (NB * NB);
    hipLaunchKernelGGL(spd_expmap_mfma, dim3(nmat), dim3(TPB), 0, stream, in, out);
}